// Round 1
// baseline (225.307 us; speedup 1.0000x reference)
//
#include <hip/hip_runtime.h>
#include <cstddef>

// ---------------- problem constants ----------------
#define B_      4096
#define V_      778
#define J_      16
#define NB_     10
#define NC_     45
#define NROWS   2334      // V*3  (n = 3*v + d)
#define PM_     135       // 9*(J-1)
#define K_TOT   145       // NB_ + PM_

// ---------------- workspace layout (floats) ----------------
// harness poisons ws each launch; every region is fully written before read.
#define WS_JS   0                           // 480 : J_reg @ shapedirs  (16,3,10)
#define WS_JT   480                         // 48  : J_reg @ v_template (16,3)
#define WS_ROT  1024                        // B*144 : rot mats (b,16,3,3)
#define WS_PM   (WS_ROT + (size_t)B_*144)   // B*135 : pose_map
#define WS_J    (WS_PM  + (size_t)B_*135)   // B*48  : joints (b,16,3)
#define WS_A2   (WS_J   + (size_t)B_*48)    // B*192 : results2 (b,16,3,4)
#define WS_VP   (WS_A2  + (size_t)B_*192)   // B*2334: v_posed
// total = 11,686,912 floats = 46.7 MB

// =====================================================================
// Kernel 1: batch-independent hoist. JS[i,d,k] = sum_v Jreg[i,v]*shd[v,d,k]
//           Jt[i,d] = sum_v Jreg[i,v]*tmpl[v,d].  One wave per output.
// =====================================================================
__global__ __launch_bounds__(256) void k_js(const float* __restrict__ jreg,
                                            const float* __restrict__ shd,
                                            const float* __restrict__ tmpl,
                                            float* __restrict__ ws)
{
    int wid  = (blockIdx.x * 256 + threadIdx.x) >> 6;   // 528 waves
    int lane = threadIdx.x & 63;
    if (wid >= 528) return;
    float s = 0.f;
    if (wid < 480) {
        int i = wid / 30, rem = wid % 30, d = rem / 10, k = rem % 10;
        const float* jr = jreg + i * V_;
        for (int v = lane; v < V_; v += 64) s += jr[v] * shd[v*30 + d*10 + k];
    } else {
        int e = wid - 480, i = e / 3, d = e % 3;
        const float* jr = jreg + i * V_;
        for (int v = lane; v < V_; v += 64) s += jr[v] * tmpl[v*3 + d];
    }
    #pragma unroll
    for (int off = 32; off; off >>= 1) s += __shfl_down(s, off, 64);
    if (lane == 0) ws[wid];   // (index identical for both ranges)
    if (lane == 0) ws[wid] = s;
}

// =====================================================================
// Kernel 2a: per (b, joint): hand-pose matvec, rodrigues, pose_map, joints j
// =====================================================================
__global__ __launch_bounds__(256) void k_rod(const float* __restrict__ pc,
                                             const float* __restrict__ betas,
                                             const float* __restrict__ sc,   // (45,45)
                                             const float* __restrict__ hm,   // (45)
                                             float* __restrict__ ws)
{
    __shared__ float scs[NC_*45 + 45];
    for (int i = threadIdx.x; i < NC_*45 + 45; i += 256)
        scs[i] = (i < NC_*45) ? sc[i] : hm[i - NC_*45];
    __syncthreads();

    int gid = blockIdx.x * 256 + threadIdx.x;   // B*16 threads exactly
    int b = gid >> 4, i = gid & 15;
    const float* pcb = pc + b * 48;

    float a0, a1, a2;
    if (i == 0) { a0 = pcb[0]; a1 = pcb[1]; a2 = pcb[2]; }
    else {
        int col = (i - 1) * 3;
        float s0 = scs[NC_*45 + col], s1 = scs[NC_*45 + col + 1], s2 = scs[NC_*45 + col + 2];
        for (int k = 0; k < NC_; ++k) {
            float p = pcb[3 + k];
            s0 += p * scs[k*45 + col];
            s1 += p * scs[k*45 + col + 1];
            s2 += p * scs[k*45 + col + 2];
        }
        a0 = s0; a1 = s1; a2 = s2;
    }
    // rodrigues — mirror reference numerics exactly
    float e0 = a0 + 1e-8f, e1 = a1 + 1e-8f, e2 = a2 + 1e-8f;
    float angle = sqrtf(e0*e0 + e1*e1 + e2*e2);
    float inv  = 1.f / angle;
    float half = 0.5f * angle;
    float sh = sinf(half), ch = cosf(half);
    float w = ch, x = sh * a0 * inv, y = sh * a1 * inv, z = sh * a2 * inv;
    float qn = 1.f / sqrtf(w*w + x*x + y*y + z*z);
    w *= qn; x *= qn; y *= qn; z *= qn;
    float w2 = w*w, x2 = x*x, y2 = y*y, z2 = z*z;
    float wx = w*x, wy = w*y, wz = w*z, xy = x*y, xz = x*z, yz = y*z;
    float R[9] = { w2+x2-y2-z2, 2*xy-2*wz,   2*wy+2*xz,
                   2*wz+2*xy,   w2-x2+y2-z2, 2*yz-2*wx,
                   2*xz-2*wy,   2*wx+2*yz,   w2-x2-y2+z2 };

    float* rot = ws + WS_ROT + (size_t)b*144 + i*9;
    #pragma unroll
    for (int q = 0; q < 9; ++q) rot[q] = R[q];
    if (i > 0) {
        float* pm = ws + WS_PM + (size_t)b*PM_ + (i-1)*9;
        #pragma unroll
        for (int q = 0; q < 9; ++q)
            pm[q] = R[q] - ((q == 0 || q == 4 || q == 8) ? 1.f : 0.f);
    }
    // joints: j[b,i,d] = Jt[i,d] + JS[i,d,:] . betas[b,:]
    const float* bb = betas + b * NB_;
    float* jout = ws + WS_J + (size_t)b*48 + i*3;
    #pragma unroll
    for (int d = 0; d < 3; ++d) {
        const float* jsrow = ws + WS_JS + (i*3 + d) * NB_;
        float s = ws[WS_JT + i*3 + d];
        #pragma unroll
        for (int k = 0; k < NB_; ++k) s += jsrow[k] * bb[k];
        jout[d] = s;
    }
}

// =====================================================================
// Kernel 2b: kinematic chain, one thread per batch.
// Writes A2 (results2, 3x4 per joint) and the 16 joint entries of jtr.
// =====================================================================
__device__ inline void emit_joint(float* __restrict__ a2, float* __restrict__ jt,
                                  int i, int invk, const float T[12], const float ji[3],
                                  const float tr[3])
{
    #pragma unroll
    for (int m = 0; m < 3; ++m) {
        float corr = T[m*4+0]*ji[0] + T[m*4+1]*ji[1] + T[m*4+2]*ji[2];
        a2[i*12 + m*4 + 0] = T[m*4+0];
        a2[i*12 + m*4 + 1] = T[m*4+1];
        a2[i*12 + m*4 + 2] = T[m*4+2];
        a2[i*12 + m*4 + 3] = T[m*4+3] - corr;
    }
    #pragma unroll
    for (int d = 0; d < 3; ++d) jt[invk*3 + d] = (T[d*4+3] + tr[d]) * 1000.f;
}

__global__ __launch_bounds__(256) void k_chain(const float* __restrict__ trans,
                                               float* __restrict__ ws,
                                               float* __restrict__ out_jtr)
{
    int b = blockIdx.x * 256 + threadIdx.x;   // exactly B_
    const float* rot = ws + WS_ROT + (size_t)b*144;
    const float* j   = ws + WS_J   + (size_t)b*48;
    float* a2 = ws + WS_A2 + (size_t)b*192;
    float* jt = out_jtr + (size_t)b*63;
    const float tr[3] = { trans[b*3], trans[b*3+1], trans[b*3+2] };
    // inverse of REORDER for pre-indices 0..15
    const int INV[16] = {0,5,6,7,9,10,11,17,18,19,13,14,15,1,2,3};

    float T0[12];
    float j0[3] = { j[0], j[1], j[2] };
    #pragma unroll
    for (int m = 0; m < 3; ++m) {
        T0[m*4+0] = rot[m*3+0]; T0[m*4+1] = rot[m*3+1];
        T0[m*4+2] = rot[m*3+2]; T0[m*4+3] = j0[m];
    }
    emit_joint(a2, jt, 0, INV[0], T0, j0, tr);

    for (int f = 0; f < 5; ++f) {       // 5 independent finger chains
        float Tp[12];
        #pragma unroll
        for (int q = 0; q < 12; ++q) Tp[q] = T0[q];
        float jp[3] = { j0[0], j0[1], j0[2] };
        for (int s = 0; s < 3; ++s) {
            int i = f*3 + 1 + s;
            const float* R = rot + i*9;
            float ji[3] = { j[i*3], j[i*3+1], j[i*3+2] };
            float d0 = ji[0]-jp[0], d1 = ji[1]-jp[1], d2 = ji[2]-jp[2];
            float Tc[12];
            #pragma unroll
            for (int m = 0; m < 3; ++m) {
                float p0 = Tp[m*4], p1 = Tp[m*4+1], p2 = Tp[m*4+2];
                Tc[m*4+0] = p0*R[0] + p1*R[3] + p2*R[6];
                Tc[m*4+1] = p0*R[1] + p1*R[4] + p2*R[7];
                Tc[m*4+2] = p0*R[2] + p1*R[5] + p2*R[8];
                Tc[m*4+3] = p0*d0 + p1*d1 + p2*d2 + Tp[m*4+3];
            }
            emit_joint(a2, jt, i, INV[i], Tc, ji, tr);
            #pragma unroll
            for (int q = 0; q < 12; ++q) Tp[q] = Tc[q];
            jp[0] = ji[0]; jp[1] = ji[1]; jp[2] = ji[2];
        }
    }
}

// =====================================================================
// Kernel 3: v_posed GEMM.  vp[b,n] = tmpl[n] + shd(n,:)·betas[b] + pdr(n,:)·pm[b]
// M=4096 (b), N=2334 (n), K=145. 64x64 tile, K chunked 73/72, pad 68.
// =====================================================================
#define LPAD 68
__global__ __launch_bounds__(256) void k_vposed(const float* __restrict__ betas,
                                                const float* __restrict__ shd,   // (2334,10)
                                                const float* __restrict__ pdr,   // (2334,135)
                                                const float* __restrict__ tmpl,  // (2334)
                                                float* __restrict__ ws)
{
    __shared__ float At[73 * LPAD];
    __shared__ float Bt[73 * LPAD];
    const float* pm = ws + WS_PM;
    float* vp = ws + WS_VP;

    const int tid = threadIdx.x;
    const int n0 = blockIdx.x * 64;
    const int b0 = blockIdx.y * 64;
    const int txn = (tid & 15) * 4;   // n offset within tile
    const int tyb = (tid >> 4) * 4;   // batch offset within tile

    float acc[4][4] = {};
    for (int kc = 0; kc < K_TOT; kc += 73) {
        const int klen = (kc == 0) ? 73 : (K_TOT - 73);
        for (int idx = tid; idx < 64 * klen; idx += 256) {
            int r  = idx / klen;            // row within tile (batch or n)
            int kl = idx % klen;
            int k  = kc + kl;
            float vA = (k < NB_) ? betas[(b0 + r) * NB_ + k]
                                 : pm[(size_t)(b0 + r) * PM_ + (k - NB_)];
            At[kl * LPAD + r] = vA;
            int n = n0 + r; int nc = (n < NROWS) ? n : (NROWS - 1);
            float vB = (k < NB_) ? shd[nc * NB_ + k]
                                 : pdr[(size_t)nc * PM_ + (k - NB_)];
            Bt[kl * LPAD + r] = vB;
        }
        __syncthreads();
        #pragma unroll 1
        for (int kl = 0; kl < klen; ++kl) {
            float4 av = *(const float4*)&At[kl * LPAD + tyb];
            float4 bv = *(const float4*)&Bt[kl * LPAD + txn];
            float a_[4] = { av.x, av.y, av.z, av.w };
            float c_[4] = { bv.x, bv.y, bv.z, bv.w };
            #pragma unroll
            for (int ib = 0; ib < 4; ++ib)
                #pragma unroll
                for (int jn = 0; jn < 4; ++jn)
                    acc[ib][jn] += a_[ib] * c_[jn];
        }
        __syncthreads();
    }
    #pragma unroll
    for (int ib = 0; ib < 4; ++ib) {
        int b = b0 + tyb + ib;
        float* row = vp + (size_t)b * NROWS;
        #pragma unroll
        for (int jn = 0; jn < 4; ++jn) {
            int n = n0 + txn + jn;
            if (n < NROWS) row[n] = acc[ib][jn] + tmpl[n];
        }
    }
}

// =====================================================================
// Kernel 4: LBS blend. block = (vertex chunk, batch). A2 reads are
// wave-uniform (blockIdx.y) -> scalar loads. Writes verts + 5 jtr tips.
// =====================================================================
__global__ __launch_bounds__(256) void k_blend(const float* __restrict__ trans,
                                               const float* __restrict__ wts,  // (V,16)
                                               const float* __restrict__ ws,
                                               float* __restrict__ out)
{
    int b = blockIdx.y;
    int v = blockIdx.x * 256 + threadIdx.x;
    if (v >= V_) return;
    const float* a2 = ws + WS_A2 + (size_t)b * 192;   // uniform -> SGPR loads
    const float* vp = ws + WS_VP + (size_t)b * NROWS + v * 3;
    float p0 = vp[0], p1 = vp[1], p2 = vp[2];

    const float4* w4 = (const float4*)(wts + v * 16);
    float wreg[16];
    #pragma unroll
    for (int q = 0; q < 4; ++q) {
        float4 t = w4[q];
        wreg[q*4+0] = t.x; wreg[q*4+1] = t.y; wreg[q*4+2] = t.z; wreg[q*4+3] = t.w;
    }
    float T[12] = {};
    #pragma unroll
    for (int jj = 0; jj < J_; ++jj) {
        float wj = wreg[jj];
        #pragma unroll
        for (int q = 0; q < 12; ++q) T[q] += wj * a2[jj*12 + q];
    }
    float o0 = T[0]*p0 + T[1]*p1 + T[2]*p2  + T[3];
    float o1 = T[4]*p0 + T[5]*p1 + T[6]*p2  + T[7];
    float o2 = T[8]*p0 + T[9]*p1 + T[10]*p2 + T[11];

    float t0 = trans[b*3], t1 = trans[b*3+1], t2 = trans[b*3+2];
    float r0 = (o0 + t0) * 1000.f, r1 = (o1 + t1) * 1000.f, r2 = (o2 + t2) * 1000.f;

    float* vout = out + (size_t)b * NROWS + v * 3;
    vout[0] = r0; vout[1] = r1; vout[2] = r2;

    // finger tips -> jtr (final positions after REORDER)
    const int TIPS[5] = {745, 317, 444, 556, 673};
    const int TIPK[5] = {4, 8, 12, 16, 20};
    #pragma unroll
    for (int t = 0; t < 5; ++t) {
        if (v == TIPS[t]) {
            float* jt = out + (size_t)B_ * NROWS + (size_t)b * 63 + TIPK[t] * 3;
            jt[0] = r0; jt[1] = r1; jt[2] = r2;
        }
    }
}

// =====================================================================
extern "C" void kernel_launch(void* const* d_in, const int* in_sizes, int n_in,
                              void* d_out, int out_size, void* d_ws, size_t ws_size,
                              hipStream_t stream)
{
    const float* pc    = (const float*)d_in[0];  // (B,48)
    const float* betas = (const float*)d_in[1];  // (B,10)
    const float* trans = (const float*)d_in[2];  // (B,3)
    const float* shd   = (const float*)d_in[3];  // (V,3,10)  == (2334,10)
    const float* pdr   = (const float*)d_in[4];  // (V,3,135) == (2334,135)
    const float* tmpl  = (const float*)d_in[5];  // (V,3)
    const float* jreg  = (const float*)d_in[6];  // (16,V)
    const float* wts   = (const float*)d_in[7];  // (V,16)
    const float* sc    = (const float*)d_in[8];  // (45,45)
    const float* hm    = (const float*)d_in[9];  // (45)
    float* out = (float*)d_out;
    float* ws  = (float*)d_ws;   // needs ~46.7 MB

    hipLaunchKernelGGL(k_js,     dim3(132),      dim3(256), 0, stream, jreg, shd, tmpl, ws);
    hipLaunchKernelGGL(k_rod,    dim3(B_*16/256),dim3(256), 0, stream, pc, betas, sc, hm, ws);
    hipLaunchKernelGGL(k_chain,  dim3(B_/256),   dim3(256), 0, stream, trans, ws,
                       out + (size_t)B_ * NROWS);
    hipLaunchKernelGGL(k_vposed, dim3(37, 64),   dim3(256), 0, stream, betas, shd, pdr, tmpl, ws);
    hipLaunchKernelGGL(k_blend,  dim3(4, B_),    dim3(256), 0, stream, trans, wts, ws, out);
}